// Round 2
// baseline (336.842 us; speedup 1.0000x reference)
//
#include <hip/hip_runtime.h>

// VQ-VAE quantizer, MI355X — all inputs/outputs fp32 (per reference dtypes).
//   prep_w  : codebook -> w = emb*|std|+mean; bf16 MFMA-B-fragment layout + fp32 wnorm
//   prep_m  : M2T[o][e] = <w_e, conv_w_o> + conv_b[o]  (1x1 conv collapsed onto codes)
//   argmin_k: MFMA bf16 GEMM dots(z,w); d = wnorm - 2*dot; fused Sum(z^2, fp32),
//             Sum(d_min), histogram, idx[]
//   out_k   : out[b,o,pos] = M2T[o][idx[b,pos]]  (gather + 128MB fp32 write)
//   fin_k   : loss + perplexity scalars

#define C_DIM 512
#define N_E   256
#define HW    4096
#define SA    132   // A_lds row stride (elems): 2-way-only bank aliasing on frag reads (free)

typedef unsigned short u16;
typedef u16   u16x4 __attribute__((ext_vector_type(4)));
typedef short s16x8 __attribute__((ext_vector_type(8)));   // bf16 MFMA fragment (4 VGPRs)
typedef float f32x4 __attribute__((ext_vector_type(4)));

__device__ __forceinline__ u16 f2bf(float f) {
    unsigned u = __float_as_uint(f);
    return (u16)((u + 0x7FFFu + ((u >> 16) & 1u)) >> 16);   // RNE
}

// ---------------- prep_w: codebook -> fragment layout + wnorm ----------------
// wfrag element (code c, k): ntg=c>>4, lane=(c&15)|(((k>>3)&3)<<4), ksg=k>>5, j=k&7
__global__ void prep_w(const float* __restrict__ emb, const float* __restrict__ stdp,
                       const float* __restrict__ means,
                       u16* __restrict__ wfrag, float* __restrict__ wnorm) {
    int c = blockIdx.x;          // code
    int t = threadIdx.x;         // 256 threads
    float stdv = fabsf(stdp[0]);
    float meanv = (means[0] + means[1] + means[2]) * (1.0f / 3.0f);
    float ss = 0.f;
    for (int k = t; k < C_DIM; k += 256) {
        float w = emb[c * C_DIM + k] * stdv + meanv;
        ss += w * w;                               // fp32 norm (matches np ref)
        int ntg  = c >> 4;
        int lane = (c & 15) | (((k >> 3) & 3) << 4);
        int ksg  = k >> 5;
        int j    = k & 7;
        wfrag[((ntg * 16 + ksg) * 64 + lane) * 8 + j] = f2bf(w);
    }
    #pragma unroll
    for (int m = 1; m < 64; m <<= 1) ss += __shfl_xor(ss, m, 64);
    __shared__ float red[4];
    if ((t & 63) == 0) red[t >> 6] = ss;
    __syncthreads();
    if (t == 0) wnorm[c] = red[0] + red[1] + red[2] + red[3];
}

// ---------------- prep_m: M2T[o*256+e] = dot(w_e, conv_w_o) + conv_b[o] ------
__global__ void prep_m(const float* __restrict__ emb, const float* __restrict__ stdp,
                       const float* __restrict__ means, const float* __restrict__ convw,
                       const float* __restrict__ convb, float* __restrict__ M2T) {
    int e = blockIdx.x;
    int t = threadIdx.x;
    int wave = t >> 6, lane = t & 63;
    __shared__ float wrow[C_DIM];
    float stdv = fabsf(stdp[0]);
    float meanv = (means[0] + means[1] + means[2]) * (1.0f / 3.0f);
    for (int k = t; k < C_DIM; k += 256) wrow[k] = emb[e * C_DIM + k] * stdv + meanv;
    __syncthreads();
    int oo = lane >> 3;          // 8 output rows per wave, 8 lanes each
    int kk = (lane & 7) * 8;     // lane's 32B strip of the row (coalesced 256B runs)
    for (int pass = 0; pass < 16; ++pass) {
        int o = pass * 32 + wave * 8 + oo;
        const float* cw = convw + o * C_DIM;
        float acc = 0.f;
        #pragma unroll
        for (int k0 = 0; k0 < C_DIM; k0 += 64) {
            f32x4 a = *(const f32x4*)(cw + k0 + kk);
            f32x4 b = *(const f32x4*)(cw + k0 + kk + 4);
            #pragma unroll
            for (int j = 0; j < 4; ++j) acc += wrow[k0 + kk + j] * a[j];
            #pragma unroll
            for (int j = 0; j < 4; ++j) acc += wrow[k0 + kk + 4 + j] * b[j];
        }
        acc += __shfl_xor(acc, 1, 64);
        acc += __shfl_xor(acc, 2, 64);
        acc += __shfl_xor(acc, 4, 64);
        if ((lane & 7) == 0) M2T[o * N_E + e] = acc + convb[o];
    }
}

// ---------------- argmin_k: the MFMA distance GEMM + fused reductions --------
// Block: 128 positions x all 256 codes, 4 waves (2 m-halves x 2 n-halves).
// Wave: 4 m-tiles(16) x 8 n-tiles(16), K chunked by 64 (2 MFMA k-steps/chunk).
__global__ __launch_bounds__(256, 2)
void argmin_k(const float* __restrict__ z, const u16* __restrict__ wfrag,
              const float* __restrict__ wnorm, u16* __restrict__ idxs,
              float* __restrict__ accum, unsigned int* __restrict__ hist) {
    __shared__ u16 A[64 * SA];                 // [ch][pos] bf16, 16.9 KB
    __shared__ unsigned long long lmin[128];
    __shared__ unsigned int lhist[N_E];
    __shared__ float lred[8];

    int tid = threadIdx.x;
    int wave = tid >> 6, lane = tid & 63;
    int mhalf = wave & 1, nhalf = wave >> 1;
    int bb = blockIdx.x;                       // 512 blocks; b = bb>>5, p0 = (bb&31)*128
    const float* zb = z + (size_t)(bb >> 5) * (C_DIM * HW) + (bb & 31) * 128;

    if (tid < 128) lmin[tid] = ~0ull;
    lhist[tid] = 0u;

    f32x4 acc[4][8];
    #pragma unroll
    for (int mt = 0; mt < 4; ++mt)
        #pragma unroll
        for (int nt = 0; nt < 8; ++nt)
            acc[mt][nt] = (f32x4){0.f, 0.f, 0.f, 0.f};

    // staging: thread = (s_ch 0..15, s_pg 0..15) handles 8 positions of 1 channel
    int s_ch = tid >> 4, s_pg = tid & 15;
    const float* gsrc = zb + s_ch * HW + s_pg * 8;
    u16* ldst = &A[s_ch * SA + s_pg * 8];
    float zs = 0.f;

    int m15 = lane & 15, quad = lane >> 4;
    int abase = mhalf * 64 + m15;
    typedef u16 u16x8 __attribute__((ext_vector_type(8)));
    const u16x8* wf8 = (const u16x8*)wfrag;

    for (int kc = 0; kc < 8; ++kc) {
        __syncthreads();                        // previous chunk's readers done
        f32x4 sv[4][2];
        #pragma unroll
        for (int it = 0; it < 4; ++it) {
            const float* p = gsrc + (size_t)(kc * 64 + it * 16) * HW;
            sv[it][0] = *(const f32x4*)(p);
            sv[it][1] = *(const f32x4*)(p + 4);
        }
        #pragma unroll
        for (int it = 0; it < 4; ++it) {
            u16x4 p0, p1;
            #pragma unroll
            for (int j = 0; j < 4; ++j) {
                float f0 = sv[it][0][j]; zs += f0 * f0; p0[j] = f2bf(f0);
                float f1 = sv[it][1][j]; zs += f1 * f1; p1[j] = f2bf(f1);
            }
            *(u16x4*)(ldst + it * 16 * SA)     = p0;   // 8B-aligned ds_write_b64
            *(u16x4*)(ldst + it * 16 * SA + 4) = p1;
        }
        __syncthreads();                        // A ready
        #pragma unroll
        for (int ks = 0; ks < 2; ++ks) {
            s16x8 bfr[8];                       // B frags straight from global (L2-hot)
            #pragma unroll
            for (int nt = 0; nt < 8; ++nt) {
                int ntg = nhalf * 8 + nt, ksg = kc * 2 + ks;
                bfr[nt] = __builtin_bit_cast(s16x8, wf8[(ntg * 16 + ksg) * 64 + lane]);
            }
            s16x8 am[4];                        // A frags: 8x ds_read_u16 each
            #pragma unroll
            for (int mt = 0; mt < 4; ++mt) {
                union { u16x8 v8; u16 s[8]; } ua;
                #pragma unroll
                for (int j = 0; j < 8; ++j)
                    ua.s[j] = A[(ks * 32 + quad * 8 + j) * SA + abase + mt * 16];
                am[mt] = __builtin_bit_cast(s16x8, ua.v8);
            }
            #pragma unroll
            for (int mt = 0; mt < 4; ++mt)
                #pragma unroll
                for (int nt = 0; nt < 8; ++nt)
                    acc[mt][nt] = __builtin_amdgcn_mfma_f32_16x16x32_bf16(
                        am[mt], bfr[nt], acc[mt][nt], 0, 0, 0);
        }
    }

    // ---- scoring: d = wnorm - 2*dot; argmin with lowest-index tie-break ----
    float wn[8];
    #pragma unroll
    for (int nt = 0; nt < 8; ++nt) wn[nt] = wnorm[(nhalf * 8 + nt) * 16 + m15];

    #pragma unroll
    for (int mt = 0; mt < 4; ++mt) {
        #pragma unroll
        for (int r = 0; r < 4; ++r) {
            unsigned long long key = ~0ull;
            #pragma unroll
            for (int nt = 0; nt < 8; ++nt) {
                float d = wn[nt] - 2.0f * acc[mt][nt][r];
                unsigned u = __float_as_uint(d);
                u ^= (u >> 31) ? 0xFFFFFFFFu : 0x80000000u;   // monotone float->uint
                unsigned code = (unsigned)((nhalf * 8 + nt) * 16 + m15);
                unsigned long long k2 = ((unsigned long long)u << 32) | code;
                key = (k2 < key) ? k2 : key;
            }
            #pragma unroll
            for (int sm = 1; sm < 16; sm <<= 1) {             // reduce across m15
                unsigned long long o2 = (unsigned long long)__shfl_xor((long long)key, sm, 64);
                key = (o2 < key) ? o2 : key;
            }
            if (m15 == 0) {
                int pos = mhalf * 64 + mt * 16 + quad * 4 + r;
                atomicMin(&lmin[pos], key);
            }
        }
    }
    __syncthreads();

    float dsum = 0.f;
    if (tid < 128) {
        unsigned long long key = lmin[tid];
        unsigned code = (unsigned)(key & 0xFFFFu);
        unsigned u = (unsigned)(key >> 32);
        u ^= (u >> 31) ? 0x80000000u : 0xFFFFFFFFu;           // inverse transform
        dsum = __uint_as_float(u);
        idxs[bb * 128 + tid] = (u16)code;
        atomicAdd(&lhist[code], 1u);
    }
    #pragma unroll
    for (int sm = 1; sm < 64; sm <<= 1) {
        dsum += __shfl_xor(dsum, sm, 64);
        zs   += __shfl_xor(zs, sm, 64);
    }
    if (lane == 0) { lred[wave] = dsum; lred[4 + wave] = zs; }
    __syncthreads();
    if (tid == 0) {
        atomicAdd(&accum[0], lred[4] + lred[5] + lred[6] + lred[7]);  // Sum z^2
        atomicAdd(&accum[1], lred[0] + lred[1] + lred[2] + lred[3]);  // Sum d_min
    }
    unsigned cnt = lhist[tid];
    if (cnt) atomicAdd(&hist[tid], cnt);
}

// ---------------- out_k: out[b,o,pos] = M2T[o][idx[b,pos]] -------------------
__global__ __launch_bounds__(256)
void out_k(const float* __restrict__ M2T, const u16* __restrict__ idxs,
           float* __restrict__ out) {
    __shared__ float col[N_E];
    int bk = blockIdx.x;                 // [b:4][o:9][q:2]
    int q = bk & 3, o = (bk >> 2) & 511, b = bk >> 11;
    col[threadIdx.x] = M2T[o * N_E + threadIdx.x];
    __syncthreads();
    int pos = q * 1024 + threadIdx.x * 4;
    u16x4 ids = *(const u16x4*)(idxs + b * HW + pos);
    f32x4 r;
    #pragma unroll
    for (int j = 0; j < 4; ++j) r[j] = col[ids[j]];
    *(f32x4*)(out + (size_t)b * (C_DIM * HW) + o * HW + pos) = r;
}

// ---------------- fin_k: loss + perplexity ----------------------------------
__global__ void fin_k(const float* __restrict__ accum, const unsigned int* __restrict__ hist,
                      float* __restrict__ outs) {
    int t = threadIdx.x;
    float e = (float)hist[t] * (1.0f / 65536.0f);
    float term = e * logf(e + 1e-10f);
    #pragma unroll
    for (int m = 1; m < 64; m <<= 1) term += __shfl_xor(term, m, 64);
    __shared__ float red[4];
    if ((t & 63) == 0) red[t >> 6] = term;
    __syncthreads();
    if (t == 0) {
        float s = red[0] + red[1] + red[2] + red[3];
        outs[0] = 1.25f * (accum[0] + accum[1]) * (1.0f / 33554432.0f);  // loss
        outs[1] = expf(-s);                                              // perplexity
    }
}

extern "C" void kernel_launch(void* const* d_in, const int* in_sizes, int n_in,
                              void* d_out, int out_size, void* d_ws, size_t ws_size,
                              hipStream_t stream) {
    (void)in_sizes; (void)n_in; (void)out_size; (void)ws_size;
    const float* z     = (const float*)d_in[0];   // [16][512][64][64] fp32
    const float* emb   = (const float*)d_in[1];   // [256][512] fp32
    const float* stdp  = (const float*)d_in[2];   // scalar
    const float* means = (const float*)d_in[3];   // [3]
    const float* convw = (const float*)d_in[4];   // [512][512] fp32
    const float* convb = (const float*)d_in[5];   // [512]

    char* ws = (char*)d_ws;
    u16*   wfrag = (u16*)(ws + 0);            // 262144 B (bf16 B-fragments)
    float* wnorm = (float*)(ws + 262144);     // 1024 B
    float* M2T   = (float*)(ws + 263168);     // 524288 B  [o][e]
    u16*   idxs  = (u16*)(ws + 787456);       // 131072 B
    float* accum = (float*)(ws + 918528);     // 8 B  [zsq, dsum]
    unsigned int* hist = (unsigned int*)(ws + 918536);  // 1024 B
    float* out = (float*)d_out;

    hipMemsetAsync(ws + 918528, 0, 1032, stream);
    prep_w  <<<256,   256, 0, stream>>>(emb, stdp, means, wfrag, wnorm);
    prep_m  <<<256,   256, 0, stream>>>(emb, stdp, means, convw, convb, M2T);
    argmin_k<<<512,   256, 0, stream>>>(z, wfrag, wnorm, idxs, accum, hist);
    out_k   <<<32768, 256, 0, stream>>>(M2T, idxs, out);
    fin_k   <<<1,     256, 0, stream>>>(accum, hist, out + 33554432);
}

// Round 3
// 290.535 us; speedup vs baseline: 1.1594x; 1.1594x over previous
//
#include <hip/hip_runtime.h>

// VQ-VAE quantizer, MI355X — fp32 I/O. 4 launches:
//   prep_w  : codebook -> bf16 MFMA-B-fragment layout + fp32 wnorm; block 0 zeroes accum/hist
//   prep_m  : M2T[o][e] = <w_e, conv_w_o> + conv_b[o] via bf16 MFMA (reuses wfrag as B)
//   argmin_k: pipelined MFMA distance GEMM (VGPR prefetch across barrier, dbuf LDS,
//             pos-major swizzled A-tile -> ds_read_b128 frags) + fused z^2/d_min/hist/idx
//   out_k   : out[b,o,:] = M2T[o][idx[b,:]] (128MB write-bound); block 0 computes loss+perplexity

#define C_DIM 512
#define N_E   256
#define HW    4096
#define SAr   72    // A_lds row stride in u16 (64 + 8 pad): 16B-aligned rows for ds_read_b128

typedef unsigned short u16;
typedef u16   u16x4 __attribute__((ext_vector_type(4)));
typedef u16   u16x8 __attribute__((ext_vector_type(8)));
typedef short s16x8 __attribute__((ext_vector_type(8)));   // bf16 MFMA fragment (4 VGPRs)
typedef float f32x4 __attribute__((ext_vector_type(4)));

__device__ __forceinline__ u16 f2bf(float f) {
    unsigned u = __float_as_uint(f);
    return (u16)((u + 0x7FFFu + ((u >> 16) & 1u)) >> 16);   // RNE
}

// ---------------- prep_w: codebook -> B-fragment layout + wnorm --------------
// wfrag element (code c, k): ntg=c>>4, lane=(c&15)|(((k>>3)&3)<<4), ksg=k>>5, j=k&7
__global__ void prep_w(const float* __restrict__ emb, const float* __restrict__ stdp,
                       const float* __restrict__ means,
                       u16* __restrict__ wfrag, float* __restrict__ wnorm,
                       float* __restrict__ accum, unsigned int* __restrict__ hist) {
    int c = blockIdx.x;          // code
    int t = threadIdx.x;         // 256 threads
    if (c == 0) {                // zero the reduction scratch (re-poisoned each call)
        hist[t] = 0u;
        if (t < 2) accum[t] = 0.f;
    }
    float stdv = fabsf(stdp[0]);
    float meanv = (means[0] + means[1] + means[2]) * (1.0f / 3.0f);
    float ss = 0.f;
    for (int k = t; k < C_DIM; k += 256) {
        float w = emb[c * C_DIM + k] * stdv + meanv;
        ss += w * w;                               // fp32 norm (matches np ref)
        int ntg  = c >> 4;
        int lane = (c & 15) | (((k >> 3) & 3) << 4);
        int ksg  = k >> 5;
        int j    = k & 7;
        wfrag[((ntg * 16 + ksg) * 64 + lane) * 8 + j] = f2bf(w);
    }
    #pragma unroll
    for (int m = 1; m < 64; m <<= 1) ss += __shfl_xor(ss, m, 64);
    __shared__ float red[4];
    if ((t & 63) == 0) red[t >> 6] = ss;
    __syncthreads();
    if (t == 0) wnorm[c] = red[0] + red[1] + red[2] + red[3];
}

// ---------------- prep_m: M2T = conv_w x w^T via bf16 MFMA -------------------
// 16 blocks x 1 wave; block = 32 o-rows x 256 e. |M2T|~1e-3, threshold 5.06 -> bf16 fine.
__global__ __launch_bounds__(64)
void prep_m(const float* __restrict__ convw, const u16* __restrict__ wfrag,
            const float* __restrict__ convb, float* __restrict__ M2T) {
    int lane = threadIdx.x;
    int m15 = lane & 15, quad = lane >> 4;
    int o0 = blockIdx.x * 32;
    const u16x8* wf8 = (const u16x8*)wfrag;

    f32x4 acc[2][16];
    #pragma unroll
    for (int mt = 0; mt < 2; ++mt)
        #pragma unroll
        for (int nt = 0; nt < 16; ++nt)
            acc[mt][nt] = (f32x4){0.f, 0.f, 0.f, 0.f};

    for (int ksg = 0; ksg < 16; ++ksg) {
        s16x8 am[2];
        #pragma unroll
        for (int mt = 0; mt < 2; ++mt) {
            const float* p = convw + (o0 + mt * 16 + m15) * C_DIM + ksg * 32 + quad * 8;
            f32x4 a = *(const f32x4*)p, b = *(const f32x4*)(p + 4);
            union { u16x8 v8; u16 s[8]; } ua;
            #pragma unroll
            for (int j = 0; j < 4; ++j) { ua.s[j] = f2bf(a[j]); ua.s[4 + j] = f2bf(b[j]); }
            am[mt] = __builtin_bit_cast(s16x8, ua.v8);
        }
        #pragma unroll
        for (int nt = 0; nt < 16; ++nt) {
            s16x8 bfr = __builtin_bit_cast(s16x8, wf8[(nt * 16 + ksg) * 64 + lane]);
            #pragma unroll
            for (int mt = 0; mt < 2; ++mt)
                acc[mt][nt] = __builtin_amdgcn_mfma_f32_16x16x32_bf16(am[mt], bfr, acc[mt][nt], 0, 0, 0);
        }
    }
    // C/D: col(e)=lane&15 (+nt*16), row(o)=quad*4+reg (+o0+mt*16)
    #pragma unroll
    for (int mt = 0; mt < 2; ++mt)
        #pragma unroll
        for (int r = 0; r < 4; ++r) {
            int o = o0 + mt * 16 + quad * 4 + r;
            float cb = convb[o];
            #pragma unroll
            for (int nt = 0; nt < 16; ++nt)
                M2T[o * N_E + nt * 16 + m15] = acc[mt][nt][r] + cb;
        }
}

// ---------------- argmin_k: pipelined MFMA distance GEMM ---------------------
// Block: 128 pos x 256 codes, 4 waves (2 m-halves x 2 n-halves); K chunks of 64 ch.
// A-tile LDS: pos-major [pos][ch^swz], SAr=72; swz: ch8blk ^= ((pos>>3)&7)<<3.
__global__ __launch_bounds__(256, 2)
void argmin_k(const float* __restrict__ z, const u16* __restrict__ wfrag,
              const float* __restrict__ wnorm, u16* __restrict__ idxs,
              float* __restrict__ accum, unsigned int* __restrict__ hist) {
    __shared__ u16 Ab[2][128 * SAr];           // 2 x 18 KB
    __shared__ unsigned long long lmin[128];
    __shared__ unsigned int lhist[N_E];
    __shared__ float lred[8];

    int tid = threadIdx.x;
    int wave = tid >> 6, lane = tid & 63;
    int mhalf = wave & 1, nhalf = wave >> 1;
    int bb = blockIdx.x;                       // 512 blocks; b = bb>>5, p0 = (bb&31)*128
    const float* zb = z + (size_t)(bb >> 5) * (C_DIM * HW) + (bb & 31) * 128;

    if (tid < 128) lmin[tid] = ~0ull;
    lhist[tid] = 0u;

    f32x4 acc[4][8];
    #pragma unroll
    for (int mt = 0; mt < 4; ++mt)
        #pragma unroll
        for (int nt = 0; nt < 8; ++nt)
            acc[mt][nt] = (f32x4){0.f, 0.f, 0.f, 0.f};

    // staging: thread = (cg 0..7: 8-ch group, t5 0..31: 4-pos group)
    int t5 = tid & 31, cg = tid >> 5;
    const float* gsrc = zb + (size_t)(cg * 8) * HW + t5 * 4;
    int skey = (t5 >> 1) & 7;                  // == (pos>>3)&7 for this thread's 4 pos
    int wch  = (cg * 8) ^ (skey * 8);
    float zs = 0.f;

    int m15 = lane & 15, quad = lane >> 4;
    const u16x8* wf8 = (const u16x8*)wfrag;

    f32x4 sv[8];
    #pragma unroll
    for (int i = 0; i < 8; ++i) sv[i] = *(const f32x4*)(gsrc + (size_t)i * HW);
    // convert + store chunk 0 into buf 0
    #pragma unroll
    for (int p = 0; p < 4; ++p) {
        u16x8 pk;
        #pragma unroll
        for (int i = 0; i < 8; ++i) { float f = sv[i][p]; zs += f * f; pk[i] = f2bf(f); }
        *(u16x8*)(&Ab[0][(t5 * 4 + p) * SAr + wch]) = pk;
    }

    for (int kc = 0; kc < 8; ++kc) {
        int cur = kc & 1;
        if (kc < 7) {                           // prefetch next chunk (stays in flight
            const float* g2 = gsrc + (size_t)((kc + 1) * 64) * HW;  // across the barrier:
            #pragma unroll                      // no global stores in this loop)
            for (int i = 0; i < 8; ++i) sv[i] = *(const f32x4*)(g2 + (size_t)i * HW);
        }
        __syncthreads();                        // Ab[cur] ready for all waves
        #pragma unroll
        for (int ks = 0; ks < 2; ++ks) {
            s16x8 bfr[8];                       // B frags from global (L2-hot, 256 KB total)
            #pragma unroll
            for (int nt = 0; nt < 8; ++nt) {
                int ntg = nhalf * 8 + nt, ksg = kc * 2 + ks;
                bfr[nt] = __builtin_bit_cast(s16x8, wf8[(ntg * 16 + ksg) * 64 + lane]);
            }
            s16x8 am[4];                        // A frags: one ds_read_b128 each
            #pragma unroll
            for (int mt = 0; mt < 4; ++mt) {
                int pos = mhalf * 64 + mt * 16 + m15;
                int rkey = (mt * 2 + (m15 >> 3)) & 7;         // == (pos>>3)&7
                int rch = (ks * 32 + quad * 8) ^ (rkey * 8);
                am[mt] = __builtin_bit_cast(s16x8, *(const u16x8*)(&Ab[cur][pos * SAr + rch]));
            }
            #pragma unroll
            for (int mt = 0; mt < 4; ++mt)
                #pragma unroll
                for (int nt = 0; nt < 8; ++nt)
                    acc[mt][nt] = __builtin_amdgcn_mfma_f32_16x16x32_bf16(
                        am[mt], bfr[nt], acc[mt][nt], 0, 0, 0);
        }
        if (kc < 7) {                           // convert + store into other buffer
            #pragma unroll
            for (int p = 0; p < 4; ++p) {
                u16x8 pk;
                #pragma unroll
                for (int i = 0; i < 8; ++i) { float f = sv[i][p]; zs += f * f; pk[i] = f2bf(f); }
                *(u16x8*)(&Ab[cur ^ 1][(t5 * 4 + p) * SAr + wch]) = pk;
            }
        }
    }

    // ---- scoring: d = wnorm - 2*dot; argmin with lowest-index tie-break ----
    float wn[8];
    #pragma unroll
    for (int nt = 0; nt < 8; ++nt) wn[nt] = wnorm[(nhalf * 8 + nt) * 16 + m15];

    #pragma unroll
    for (int mt = 0; mt < 4; ++mt) {
        #pragma unroll
        for (int r = 0; r < 4; ++r) {
            unsigned long long key = ~0ull;
            #pragma unroll
            for (int nt = 0; nt < 8; ++nt) {
                float d = wn[nt] - 2.0f * acc[mt][nt][r];
                unsigned u = __float_as_uint(d);
                u ^= (u >> 31) ? 0xFFFFFFFFu : 0x80000000u;   // monotone float->uint
                unsigned code = (unsigned)((nhalf * 8 + nt) * 16 + m15);
                unsigned long long k2 = ((unsigned long long)u << 32) | code;
                key = (k2 < key) ? k2 : key;
            }
            #pragma unroll
            for (int sm = 1; sm < 16; sm <<= 1) {             // reduce across m15
                unsigned long long o2 = (unsigned long long)__shfl_xor((long long)key, sm, 64);
                key = (o2 < key) ? o2 : key;
            }
            if (m15 == 0) {
                int pos = mhalf * 64 + mt * 16 + quad * 4 + r;
                atomicMin(&lmin[pos], key);
            }
        }
    }
    __syncthreads();

    float dsum = 0.f;
    if (tid < 128) {
        unsigned long long key = lmin[tid];
        unsigned code = (unsigned)(key & 0xFFFFu);
        unsigned u = (unsigned)(key >> 32);
        u ^= (u >> 31) ? 0x80000000u : 0xFFFFFFFFu;           // inverse transform
        dsum = __uint_as_float(u);
        idxs[bb * 128 + tid] = (u16)code;
        atomicAdd(&lhist[code], 1u);
    }
    #pragma unroll
    for (int sm = 1; sm < 64; sm <<= 1) {
        dsum += __shfl_xor(dsum, sm, 64);
        zs   += __shfl_xor(zs, sm, 64);
    }
    if (lane == 0) { lred[wave] = dsum; lred[4 + wave] = zs; }
    __syncthreads();
    if (tid == 0) {
        atomicAdd(&accum[0], lred[4] + lred[5] + lred[6] + lred[7]);  // Sum z^2
        atomicAdd(&accum[1], lred[0] + lred[1] + lred[2] + lred[3]);  // Sum d_min
    }
    unsigned cnt = lhist[tid];
    if (cnt) atomicAdd(&hist[tid], cnt);
}

// ---------------- out_k: out[b,o,:] = M2T[o][idx[b,:]]; block0 adds scalars --
__global__ __launch_bounds__(256)
void out_k(const float* __restrict__ M2T, const u16* __restrict__ idxs,
           float* __restrict__ out, const float* __restrict__ accum,
           const unsigned int* __restrict__ hist) {
    __shared__ float col[N_E];
    int tid = threadIdx.x;
    int bk = blockIdx.x;                 // [b:16][o:512] -> one (b,o) plane per block
    int o = bk & 511, b = bk >> 9;
    col[tid] = M2T[o * N_E + tid];
    __syncthreads();
    size_t obase = (size_t)b * (C_DIM * HW) + (size_t)o * HW;
    #pragma unroll
    for (int j = 0; j < 4; ++j) {
        int p4 = (j * 256 + tid) * 4;
        u16x4 ids = *(const u16x4*)(idxs + b * HW + p4);
        f32x4 r;
        #pragma unroll
        for (int jj = 0; jj < 4; ++jj) r[jj] = col[ids[jj]];
        *(f32x4*)(out + obase + p4) = r;
    }
    if (bk == 0) {                       // fused scalar epilogue (loss + perplexity)
        float e = (float)hist[tid] * (1.0f / 65536.0f);
        float term = e * logf(e + 1e-10f);
        #pragma unroll
        for (int m = 1; m < 64; m <<= 1) term += __shfl_xor(term, m, 64);
        __shared__ float red[4];
        if ((tid & 63) == 0) red[tid >> 6] = term;
        __syncthreads();
        if (tid == 0) {
            float s = red[0] + red[1] + red[2] + red[3];
            out[33554432] = 1.25f * (accum[0] + accum[1]) * (1.0f / 33554432.0f);
            out[33554433] = expf(-s);
        }
    }
}

extern "C" void kernel_launch(void* const* d_in, const int* in_sizes, int n_in,
                              void* d_out, int out_size, void* d_ws, size_t ws_size,
                              hipStream_t stream) {
    (void)in_sizes; (void)n_in; (void)out_size; (void)ws_size;
    const float* z     = (const float*)d_in[0];   // [16][512][64][64] fp32
    const float* emb   = (const float*)d_in[1];   // [256][512] fp32
    const float* stdp  = (const float*)d_in[2];   // scalar
    const float* means = (const float*)d_in[3];   // [3]
    const float* convw = (const float*)d_in[4];   // [512][512] fp32
    const float* convb = (const float*)d_in[5];   // [512]

    char* ws = (char*)d_ws;
    u16*   wfrag = (u16*)(ws + 0);            // 262144 B (bf16 B-fragments)
    float* wnorm = (float*)(ws + 262144);     // 1024 B
    float* M2T   = (float*)(ws + 263168);     // 524288 B  [o][e]
    u16*   idxs  = (u16*)(ws + 787456);       // 131072 B
    float* accum = (float*)(ws + 918528);     // 8 B  [zsq, dsum]
    unsigned int* hist = (unsigned int*)(ws + 918536);  // 1024 B
    float* out = (float*)d_out;

    prep_w  <<<256,  256, 0, stream>>>(emb, stdp, means, wfrag, wnorm, accum, hist);
    prep_m  <<<16,    64, 0, stream>>>(convw, wfrag, convb, M2T);
    argmin_k<<<512,  256, 0, stream>>>(z, wfrag, wnorm, idxs, accum, hist);
    out_k   <<<8192, 256, 0, stream>>>(M2T, idxs, out, accum, hist);
}